// Round 9
// baseline (133.567 us; speedup 1.0000x reference)
//
#include <hip/hip_runtime.h>
#include <hip/hip_bf16.h>

// Problem constants
#define BATCH  8
#define SEQ    2048
#define DMODEL 1024
#define DHEAD  128

typedef __attribute__((ext_vector_type(4))) float f32x4;
typedef __attribute__((ext_vector_type(4))) float f4;
typedef _Float16 f16;
typedef __attribute__((ext_vector_type(4))) _Float16 f16x4;
typedef __attribute__((ext_vector_type(8))) _Float16 f16x8;
typedef __attribute__((ext_vector_type(8))) __bf16 bf16x8;
typedef __attribute__((ext_vector_type(8))) unsigned short u16x8;

__device__ __forceinline__ unsigned short f2bf(float f) {
    unsigned u = __builtin_bit_cast(unsigned, f);
    u += 0x7fffu + ((u >> 16) & 1u);   // round-to-nearest-even
    return (unsigned short)(u >> 16);
}

#if __has_builtin(__builtin_amdgcn_exp2f)
#define EXP2(x) __builtin_amdgcn_exp2f(x)
#else
#define EXP2(x) exp2f(x)
#endif

__device__ __forceinline__ float fast_rcp(float x) {
#if __has_builtin(__builtin_amdgcn_rcpf)
    return __builtin_amdgcn_rcpf(x);
#else
    return 1.0f / x;
#endif
}

// ---------------------------------------------------------------------------
// Kernel 0: pre-split W into fragment-linear layout (done ONCE, not per-block).
// Wsp: [mat][ks][hi][row][8] f16, mat: 0=Qh 1=Ql 2=Kh 3=Kl 4=Vh.
// A wave's MFMA B-fragment read (16 rows x one hi) is then 1KB contiguous.
// ---------------------------------------------------------------------------
__global__ __launch_bounds__(256) void wsplit_kernel(
    const float* __restrict__ WQ, const float* __restrict__ WK,
    const float* __restrict__ WV, f16* __restrict__ Wsp)
{
    const int gid = blockIdx.x * 256 + threadIdx.x;   // 0..81919
    const int row = gid & 127;
    const int hi  = (gid >> 7) & 3;
    const int ks  = (gid >> 9) & 31;
    const int mat = gid >> 14;                        // 0..4
    const float* W = (mat < 2) ? WQ : (mat < 4) ? WK : WV;
    const float* src = W + (size_t)row * DMODEL + ks * 32 + hi * 8;
    f4 v0 = *(const f4*)src, v1 = *(const f4*)(src + 4);
    const bool lopart = (mat == 1 || mat == 3);
    f16x8 o;
    #pragma unroll
    for (int j = 0; j < 4; ++j) {
        f16 h0 = (f16)v0[j], h1 = (f16)v1[j];
        o[j]     = lopart ? (f16)(v0[j] - (float)h0) : h0;
        o[j + 4] = lopart ? (f16)(v1[j] - (float)h1) : h1;
    }
    *reinterpret_cast<f16x8*>(Wsp + (size_t)gid * 8) = o;
}

// ---------------------------------------------------------------------------
// Kernel 1: FUSED projections. 8 waves (4m x 2n), BM=64, BK=32, double-
// buffered LDS, one barrier/step. W comes PRE-SPLIT fragment-linear -> LDS
// staging is a pure 16B copy (no VALU), reads are conflict-free (slot=lo&7).
// W_V hi fragments are read DIRECT from global (L2-resident) - not in LDS.
// Q,K split-f16 (f32-grade: tanh transition |s|~3 vs raw score std ~1024);
// V single MFMA -> bf16 store (range: P in [8.8e-27,1] pairs with V).
// ---------------------------------------------------------------------------
__global__ __launch_bounds__(512) void proj_kernel(
    const float* __restrict__ x, const f16* __restrict__ Wsp,
    f16* __restrict__ Qh, f16* __restrict__ Ql,
    f16* __restrict__ Kh, f16* __restrict__ Kl,
    unsigned short* __restrict__ Vtb)
{
    __shared__ f16 Wl[2][4][512][8];          // [buf][mat][(hi*128+row)][8] 64KB
    __shared__ f16 Ax[2][2][4][4][16][8];     // [buf][h/l][rb][hi][ro][8]   16KB

    const int tid  = threadIdx.x;
    const int lane = tid & 63;
    const int w    = tid >> 6;
    const int lo   = lane & 15;
    const int hi   = lane >> 4;
    const int wm   = w & 3;                   // 16-row quadrant
    const int wn   = w >> 2;                  // 64-col half
    const int m0   = blockIdx.x * 64;

    // x staging map: 64 rows x 32 cols, 4 f32/thread
    const int xrow = tid >> 3, xcg = tid & 7;
    const int xrb = xrow >> 4, xro = xrow & 15, xhi = xcg >> 1, xjo = (xcg & 1) * 4;

    f32x4 accQ[4] = {}, accK[4] = {}, accV[4] = {};

    f16x8 rw[4];
    f4 rx;

    auto load_stage = [&](int ks) {
        #pragma unroll
        for (int m = 0; m < 4; ++m)
            rw[m] = *reinterpret_cast<const f16x8*>(
                Wsp + ((size_t)(m * 32 + ks) * 4096) + tid * 8);
        rx = *(const f4*)(x + (size_t)(m0 + xrow) * DMODEL + ks * 32 + xcg * 4);
    };
    auto write_stage = [&](int buf) {
        #pragma unroll
        for (int m = 0; m < 4; ++m)
            *reinterpret_cast<f16x8*>(&Wl[buf][m][tid >> 3 << 3 | (tid & 7)][0]) = rw[m];
        f16x4 h4, l4;
        #pragma unroll
        for (int j = 0; j < 4; ++j) {
            f16 h = (f16)rx[j];
            h4[j] = h; l4[j] = (f16)(rx[j] - (float)h);
        }
        *reinterpret_cast<f16x4*>(&Ax[buf][0][xrb][xhi][xro][xjo]) = h4;
        *reinterpret_cast<f16x4*>(&Ax[buf][1][xrb][xhi][xro][xjo]) = l4;
    };

    load_stage(0);
    write_stage(0);
    __syncthreads();

    const f16* WspV = Wsp + (size_t)(4 * 32) * 4096;

    for (int ks = 0; ks < 32; ++ks) {
        const int cur = ks & 1;
        if (ks < 31) load_stage(ks + 1);

        f16x8 ah = *reinterpret_cast<const f16x8*>(&Ax[cur][0][wm][hi][lo][0]);
        f16x8 al = *reinterpret_cast<const f16x8*>(&Ax[cur][1][wm][hi][lo][0]);
        #pragma unroll
        for (int nt = 0; nt < 4; ++nt) {
            const int idx = hi * 128 + wn * 64 + nt * 16 + lo;
            f16x8 bh = *reinterpret_cast<const f16x8*>(&Wl[cur][0][idx][0]);
            f16x8 bl = *reinterpret_cast<const f16x8*>(&Wl[cur][1][idx][0]);
            accQ[nt] = __builtin_amdgcn_mfma_f32_16x16x32_f16(ah, bh, accQ[nt], 0, 0, 0);
            accQ[nt] = __builtin_amdgcn_mfma_f32_16x16x32_f16(ah, bl, accQ[nt], 0, 0, 0);
            accQ[nt] = __builtin_amdgcn_mfma_f32_16x16x32_f16(al, bh, accQ[nt], 0, 0, 0);
            bh = *reinterpret_cast<const f16x8*>(&Wl[cur][2][idx][0]);
            bl = *reinterpret_cast<const f16x8*>(&Wl[cur][3][idx][0]);
            accK[nt] = __builtin_amdgcn_mfma_f32_16x16x32_f16(ah, bh, accK[nt], 0, 0, 0);
            accK[nt] = __builtin_amdgcn_mfma_f32_16x16x32_f16(ah, bl, accK[nt], 0, 0, 0);
            accK[nt] = __builtin_amdgcn_mfma_f32_16x16x32_f16(al, bh, accK[nt], 0, 0, 0);
            f16x8 bv = *reinterpret_cast<const f16x8*>(
                WspV + (size_t)ks * 4096 + (size_t)idx * 8);
            accV[nt] = __builtin_amdgcn_mfma_f32_16x16x32_f16(ah, bv, accV[nt], 0, 0, 0);
        }
        if (ks < 31) write_stage(cur ^ 1);
        __syncthreads();
    }

    // epilogue: D layout col = lane&15, row = (lane>>4)*4 + r
    #pragma unroll
    for (int nt = 0; nt < 4; ++nt)
        #pragma unroll
        for (int r = 0; r < 4; ++r) {
            const int m = m0 + wm * 16 + hi * 4 + r;
            const int n = wn * 64 + nt * 16 + lo;
            const size_t idx = (size_t)m * DHEAD + n;
            float vq = accQ[nt][r];
            f16 hq = (f16)vq;
            Qh[idx] = hq; Ql[idx] = (f16)(vq - (float)hq);
            float vk = accK[nt][r];
            f16 hk = (f16)vk;
            Kh[idx] = hk; Kl[idx] = (f16)(vk - (float)hk);
            const int bb = m >> 11, l = m & 2047;
            Vtb[((size_t)bb * DHEAD + n) * SEQ + l] = f2bf(accV[nt][r]);
        }
}

// ---------------------------------------------------------------------------
// Kernel 2: causal tanh-capped attention, rescale-free flash.
// P = exp(30*tanh(s)-30) = exp2(-86.5617/(exp2(0.2551*s_raw)+1)) in [8.8e-27,1]
// 8 waves = (wq 0..3) x (wk 0..1); 64 q-rows/block, 64-key super-tile/iter.
// K hi/lo + V + mask in double-buffered LDS, XOR-swizzled (byte ^= (row&7)<<4
// per 16B chunk) -> 2-way max on all reads/writes (r8 layouts were 8-way).
// One barrier/iter, reg-staged. 2-way wk merge at end via LDS overlay.
// ---------------------------------------------------------------------------
#define KHS_OFF 0          // [2][64] rows * 256B  = 32768
#define KLS_OFF 32768      // [2][64] rows * 256B  = 32768
#define VS_OFF  65536      // [2][128] rows * 128B = 32768
#define MS_OFF  98304      // int[2][64]           = 512
#define PL_OFF  98816      // ushort[8][16][40]    = 10240
__global__ __launch_bounds__(512) void attn_kernel(
    const f16* __restrict__ Qh, const f16* __restrict__ Ql,
    const f16* __restrict__ Kh, const f16* __restrict__ Kl,
    const unsigned short* __restrict__ Vtb, const int* __restrict__ mask,
    float* __restrict__ out)
{
    __shared__ __align__(16) char smem[109056];
    char* khs = smem + KHS_OFF;
    char* kls = smem + KLS_OFF;
    char* vs  = smem + VS_OFF;
    int*  Ms  = (int*)(smem + MS_OFF);
    unsigned short (*Plds)[16][40] = (unsigned short (*)[16][40])(smem + PL_OFF);

    const int tid  = threadIdx.x;
    const int lane = tid & 63;
    const int w    = tid >> 6;                  // 0..7
    const int lo   = lane & 15;
    const int hi   = lane >> 4;
    const int wq   = w & 3;
    const int wk   = w >> 2;
    const int b    = blockIdx.x;
    const int qs   = 31 - (int)blockIdx.y;      // heavy blocks first
    const int qrow = qs * 64 + wq * 16;
    const int niter = qs + 1;

    const float c2p = 0.25506061907448296f;     // (2*log2e)/sqrt(128)
    const float c1  = -86.561702453337804f;     // -60*log2e

    f16x8 qh[4], ql[4];
    {
        const size_t off = ((size_t)(b * SEQ + qrow + lo)) * DHEAD + hi * 8;
        #pragma unroll
        for (int c = 0; c < 4; ++c) {
            qh[c] = *reinterpret_cast<const f16x8*>(Qh + off + c * 32);
            ql[c] = *reinterpret_cast<const f16x8*>(Ql + off + c * 32);
        }
    }

    // staging maps
    const int krow = tid >> 3;                  // 0..63
    const int kb0  = (tid & 7) * 32;            // first 16B-chunk byte in row
    const int vrow = tid >> 2;                  // 0..127
    const int vb0  = (tid & 3) * 32;

    f16x8 rKh0, rKh1, rKl0, rKl1;
    u16x8 rV0, rV1;
    int   rM = 0;

    auto load_tile = [&](int kb) {
        const size_t koff = ((size_t)(b * SEQ + kb + krow)) * DHEAD + kb0 / 2;
        rKh0 = *reinterpret_cast<const f16x8*>(Kh + koff);
        rKh1 = *reinterpret_cast<const f16x8*>(Kh + koff + 8);
        rKl0 = *reinterpret_cast<const f16x8*>(Kl + koff);
        rKl1 = *reinterpret_cast<const f16x8*>(Kl + koff + 8);
        const unsigned short* vp = Vtb + ((size_t)b * DHEAD + vrow) * SEQ + kb + vb0 / 2;
        rV0 = *reinterpret_cast<const u16x8*>(vp);
        rV1 = *reinterpret_cast<const u16x8*>(vp + 8);
        if (tid < 64) rM = mask[b * SEQ + kb + tid];
    };
    auto write_tile = [&](int buf) {
        const int swz = (krow & 7) << 4;
        char* kd = khs + buf * 16384 + krow * 256;
        *reinterpret_cast<f16x8*>(kd + ((kb0)      ^ swz)) = rKh0;
        *reinterpret_cast<f16x8*>(kd + ((kb0 + 16) ^ swz)) = rKh1;
        kd = kls + buf * 16384 + krow * 256;
        *reinterpret_cast<f16x8*>(kd + ((kb0)      ^ swz)) = rKl0;
        *reinterpret_cast<f16x8*>(kd + ((kb0 + 16) ^ swz)) = rKl1;
        const int vswz = (vrow & 7) << 4;
        char* vd = vs + buf * 16384 + vrow * 128;
        *reinterpret_cast<u16x8*>(vd + ((vb0)      ^ vswz)) = rV0;
        *reinterpret_cast<u16x8*>(vd + ((vb0 + 16) ^ vswz)) = rV1;
        if (tid < 64) Ms[buf * 64 + tid] = rM;
    };

    load_tile(0);
    write_tile(0);
    __syncthreads();

    f32x4 acc[8] = {};
    float rs[4] = {0.f, 0.f, 0.f, 0.f};

    for (int it = 0; it < niter; ++it) {
        const int cur = it & 1;
        if (it + 1 < niter) load_tile((it + 1) * 64);

        const int kb = it * 64 + wk * 32;
        if (kb <= qrow + 15) {
            const int lswz = (lo & 7) << 4;
            #pragma unroll
            for (int h = 0; h < 2; ++h) {
                const int row = wk * 32 + h * 16 + lo;
                const char* kph = khs + cur * 16384 + row * 256;
                const char* kpl = kls + cur * 16384 + row * 256;
                f32x4 s = {};
                #pragma unroll
                for (int c = 0; c < 4; ++c) {
                    const int cb = (c * 64 + hi * 16) ^ lswz;
                    f16x8 fkh = *reinterpret_cast<const f16x8*>(kph + cb);
                    f16x8 fkl = *reinterpret_cast<const f16x8*>(kpl + cb);
                    s = __builtin_amdgcn_mfma_f32_16x16x32_f16(qh[c], fkh, s, 0, 0, 0);
                    s = __builtin_amdgcn_mfma_f32_16x16x32_f16(qh[c], fkl, s, 0, 0, 0);
                    s = __builtin_amdgcn_mfma_f32_16x16x32_f16(ql[c], fkh, s, 0, 0, 0);
                }
                const int key = kb + h * 16 + lo;
                const int mk  = Ms[cur * 64 + wk * 32 + h * 16 + lo];
                #pragma unroll
                for (int r = 0; r < 4; ++r) {
                    const int q = qrow + hi * 4 + r;
                    float t = EXP2(s[r] * c2p);               // e^{2s} (inf ok)
                    float p = EXP2(c1 * fast_rcp(t + 1.0f));
                    p = (key <= q && mk != 0) ? p : 0.0f;     // causal + padding
                    rs[r] += p;
                    Plds[w][hi * 4 + r][h * 16 + lo] = f2bf(p);
                }
            }
            bf16x8 pa = *reinterpret_cast<const bf16x8*>(&Plds[w][lo][hi * 8]);
            #pragma unroll
            for (int dt = 0; dt < 8; ++dt) {
                const int row = dt * 16 + lo;
                const char* vp = vs + cur * 16384 + row * 128;
                bf16x8 vf = *reinterpret_cast<const bf16x8*>(
                    vp + ((wk * 64 + hi * 16) ^ lswz));
                acc[dt] = __builtin_amdgcn_mfma_f32_16x16x32_bf16(pa, vf, acc[dt], 0, 0, 0);
            }
        }

        if (it + 1 < niter) write_tile(cur ^ 1);
        __syncthreads();
    }

    // 2-way wk merge (overlay on K region; loop's last barrier separates)
    float* red = (float*)smem;
    if (wk == 1) {
        float* dst = red + ((size_t)wq * 64 + lane) * 36;
        #pragma unroll
        for (int dt = 0; dt < 8; ++dt)
            #pragma unroll
            for (int r = 0; r < 4; ++r) dst[dt * 4 + r] = acc[dt][r];
        #pragma unroll
        for (int r = 0; r < 4; ++r) dst[32 + r] = rs[r];
    }
    __syncthreads();
    if (wk == 0) {
        const float* src = red + ((size_t)wq * 64 + lane) * 36;
        #pragma unroll
        for (int dt = 0; dt < 8; ++dt)
            #pragma unroll
            for (int r = 0; r < 4; ++r) acc[dt][r] += src[dt * 4 + r];
        float inv[4];
        #pragma unroll
        for (int r = 0; r < 4; ++r) {
            float v = rs[r] + src[32 + r];
            v += __shfl_xor(v, 1);
            v += __shfl_xor(v, 2);
            v += __shfl_xor(v, 4);
            v += __shfl_xor(v, 8);
            inv[r] = fast_rcp(v);
        }
        #pragma unroll
        for (int dt = 0; dt < 8; ++dt)
            #pragma unroll
            for (int r = 0; r < 4; ++r) {
                const size_t q = (size_t)qrow + hi * 4 + r;
                out[((size_t)b * SEQ + q) * DHEAD + dt * 16 + lo] = acc[dt][r] * inv[r];
            }
    }
}

extern "C" void kernel_launch(void* const* d_in, const int* in_sizes, int n_in,
                              void* d_out, int out_size, void* d_ws, size_t ws_size,
                              hipStream_t stream) {
    const float* x   = (const float*)d_in[0];
    const int*   msk = (const int*)d_in[1];
    const float* WQ  = (const float*)d_in[2];
    const float* WK  = (const float*)d_in[3];
    const float* WV  = (const float*)d_in[4];
    float* out = (float*)d_out;

    // ws: Qh|Ql|Kh|Kl (f16) | Vt (bf16) 20MB | Wsp 1.31MB
    const size_t NE = (size_t)BATCH * SEQ * DHEAD;
    f16* Qh = (f16*)d_ws;
    f16* Ql = Qh + NE;
    f16* Kh = Ql + NE;
    f16* Kl = Kh + NE;
    unsigned short* Vtb = (unsigned short*)(Kl + NE);
    f16* Wsp = (f16*)(Vtb + NE);

    wsplit_kernel<<<320, 256, 0, stream>>>(WQ, WK, WV, Wsp);
    proj_kernel<<<dim3(BATCH * SEQ / 64), 512, 0, stream>>>(x, Wsp, Qh, Ql, Kh, Kl, Vtb);
    attn_kernel<<<dim3(BATCH, 32), 512, 0, stream>>>(Qh, Ql, Kh, Kl, Vtb, msk, out);
}

// Round 10
// 109.019 us; speedup vs baseline: 1.2252x; 1.2252x over previous
//
#include <hip/hip_runtime.h>
#include <hip/hip_bf16.h>

// Problem constants
#define BATCH  8
#define SEQ    2048
#define DMODEL 1024
#define DHEAD  128

typedef __attribute__((ext_vector_type(4))) float f32x4;
typedef __attribute__((ext_vector_type(4))) float f4;
typedef _Float16 f16;
typedef __attribute__((ext_vector_type(4))) _Float16 f16x4;
typedef __attribute__((ext_vector_type(8))) _Float16 f16x8;
typedef __attribute__((ext_vector_type(8))) __bf16 bf16x8;
typedef __attribute__((ext_vector_type(16))) unsigned short u16x16;

__device__ __forceinline__ unsigned short f2bf(float f) {
    unsigned u = __builtin_bit_cast(unsigned, f);
    u += 0x7fffu + ((u >> 16) & 1u);   // round-to-nearest-even
    return (unsigned short)(u >> 16);
}

#if __has_builtin(__builtin_amdgcn_exp2f)
#define EXP2(x) __builtin_amdgcn_exp2f(x)
#else
#define EXP2(x) exp2f(x)
#endif

__device__ __forceinline__ float fast_rcp(float x) {
#if __has_builtin(__builtin_amdgcn_rcpf)
    return __builtin_amdgcn_rcpf(x);
#else
    return 1.0f / x;
#endif
}

// ---------------------------------------------------------------------------
// Kernel 0: pre-split W into fragment-linear layout (ONCE).
// Wsp: [mat][ks][hi][row][8] f16, mat: 0=Qh 1=Ql 2=Kh 3=Kl 4=Vh.
// ---------------------------------------------------------------------------
__global__ __launch_bounds__(256) void wsplit_kernel(
    const float* __restrict__ WQ, const float* __restrict__ WK,
    const float* __restrict__ WV, f16* __restrict__ Wsp)
{
    const int gid = blockIdx.x * 256 + threadIdx.x;   // 0..81919
    const int row = gid & 127;
    const int hi  = (gid >> 7) & 3;
    const int ks  = (gid >> 9) & 31;
    const int mat = gid >> 14;                        // 0..4
    const float* W = (mat < 2) ? WQ : (mat < 4) ? WK : WV;
    const float* src = W + (size_t)row * DMODEL + ks * 32 + hi * 8;
    f4 v0 = *(const f4*)src, v1 = *(const f4*)(src + 4);
    const bool lopart = (mat == 1 || mat == 3);
    f16x8 o;
    #pragma unroll
    for (int j = 0; j < 4; ++j) {
        f16 h0 = (f16)v0[j], h1 = (f16)v1[j];
        o[j]     = lopart ? (f16)(v0[j] - (float)h0) : h0;
        o[j + 4] = lopart ? (f16)(v1[j] - (float)h1) : h1;
    }
    *reinterpret_cast<f16x8*>(Wsp + (size_t)gid * 8) = o;
}

// ---------------------------------------------------------------------------
// Kernel 1: FUSED projections. BM=32 -> grid 512 = 2 blocks/CU (barrier
// overlap between co-resident blocks). 8 waves; wave w owns 16 cols x all
// 32 rows (2 row-frags): per step 4 A-reads + 4 W-reads (LDS) + 1 V-frag
// (global, L2) -> 14 MFMAs. W pre-split fragment-linear; one barrier/step.
// Q,K split-f16 (f32-grade scores); V single MFMA -> bf16 (range for P*V).
// ---------------------------------------------------------------------------
__global__ __launch_bounds__(512) void proj_kernel(
    const float* __restrict__ x, const f16* __restrict__ Wsp,
    f16* __restrict__ Qh, f16* __restrict__ Ql,
    f16* __restrict__ Kh, f16* __restrict__ Kl,
    unsigned short* __restrict__ Vtb)
{
    __shared__ f16 Wl[2][4][4][128][8];       // [buf][mat][hi][row][8]  64KB
    __shared__ f16 Ax[2][2][2][4][17][8];     // [buf][h/l][rb][hi][ro17][8]

    const int tid  = threadIdx.x;
    const int lane = tid & 63;
    const int w    = tid >> 6;                // 0..7: col group (16 cols)
    const int lo   = lane & 15;
    const int hi   = lane >> 4;
    const int m0   = blockIdx.x * 32;

    const int xrow = (tid & 255) >> 3;        // 0..31
    const int xcg  = tid & 7;
    const int xrb  = xrow >> 4, xro = xrow & 15;
    const int xhi  = xcg >> 1,  xjo = (xcg & 1) * 4;

    f32x4 accQ[2] = {}, accK[2] = {}, accV[2] = {};

    f16x8 rw[4];
    f4 rx;

    auto load_stage = [&](int ks) {
        #pragma unroll
        for (int m = 0; m < 4; ++m)
            rw[m] = *reinterpret_cast<const f16x8*>(
                Wsp + (size_t)(m * 32 + ks) * 4096 + tid * 8);
        if (tid < 256)
            rx = *(const f4*)(x + (size_t)(m0 + xrow) * DMODEL + ks * 32 + xcg * 4);
    };
    auto write_stage = [&](int buf) {
        #pragma unroll
        for (int m = 0; m < 4; ++m)
            *reinterpret_cast<f16x8*>(&Wl[buf][m][0][0][0] + (size_t)tid * 8) = rw[m];
        if (tid < 256) {
            f16x4 h4, l4;
            #pragma unroll
            for (int j = 0; j < 4; ++j) {
                f16 h = (f16)rx[j];
                h4[j] = h; l4[j] = (f16)(rx[j] - (float)h);
            }
            *reinterpret_cast<f16x4*>(&Ax[buf][0][xrb][xhi][xro][xjo]) = h4;
            *reinterpret_cast<f16x4*>(&Ax[buf][1][xrb][xhi][xro][xjo]) = l4;
        }
    };

    load_stage(0);
    write_stage(0);
    __syncthreads();

    const f16* WspV = Wsp + (size_t)(4 * 32) * 4096;
    const int  fi   = hi * 128 + w * 16 + lo;   // W fragment flat index

    for (int ks = 0; ks < 32; ++ks) {
        const int cur = ks & 1;
        if (ks < 31) load_stage(ks + 1);

        f16x8 ah0 = *reinterpret_cast<const f16x8*>(&Ax[cur][0][0][hi][lo][0]);
        f16x8 al0 = *reinterpret_cast<const f16x8*>(&Ax[cur][1][0][hi][lo][0]);
        f16x8 ah1 = *reinterpret_cast<const f16x8*>(&Ax[cur][0][1][hi][lo][0]);
        f16x8 al1 = *reinterpret_cast<const f16x8*>(&Ax[cur][1][1][hi][lo][0]);

        f16x8 bh = *reinterpret_cast<const f16x8*>(&Wl[cur][0][0][0][0] + (size_t)fi * 8);
        f16x8 bl = *reinterpret_cast<const f16x8*>(&Wl[cur][1][0][0][0] + (size_t)fi * 8);
        f16x8 kh = *reinterpret_cast<const f16x8*>(&Wl[cur][2][0][0][0] + (size_t)fi * 8);
        f16x8 kl = *reinterpret_cast<const f16x8*>(&Wl[cur][3][0][0][0] + (size_t)fi * 8);
        f16x8 bv = *reinterpret_cast<const f16x8*>(WspV + (size_t)ks * 4096 + (size_t)fi * 8);

        accQ[0] = __builtin_amdgcn_mfma_f32_16x16x32_f16(ah0, bh, accQ[0], 0, 0, 0);
        accQ[0] = __builtin_amdgcn_mfma_f32_16x16x32_f16(ah0, bl, accQ[0], 0, 0, 0);
        accQ[0] = __builtin_amdgcn_mfma_f32_16x16x32_f16(al0, bh, accQ[0], 0, 0, 0);
        accQ[1] = __builtin_amdgcn_mfma_f32_16x16x32_f16(ah1, bh, accQ[1], 0, 0, 0);
        accQ[1] = __builtin_amdgcn_mfma_f32_16x16x32_f16(ah1, bl, accQ[1], 0, 0, 0);
        accQ[1] = __builtin_amdgcn_mfma_f32_16x16x32_f16(al1, bh, accQ[1], 0, 0, 0);
        accK[0] = __builtin_amdgcn_mfma_f32_16x16x32_f16(ah0, kh, accK[0], 0, 0, 0);
        accK[0] = __builtin_amdgcn_mfma_f32_16x16x32_f16(ah0, kl, accK[0], 0, 0, 0);
        accK[0] = __builtin_amdgcn_mfma_f32_16x16x32_f16(al0, kh, accK[0], 0, 0, 0);
        accK[1] = __builtin_amdgcn_mfma_f32_16x16x32_f16(ah1, kh, accK[1], 0, 0, 0);
        accK[1] = __builtin_amdgcn_mfma_f32_16x16x32_f16(ah1, kl, accK[1], 0, 0, 0);
        accK[1] = __builtin_amdgcn_mfma_f32_16x16x32_f16(al1, kh, accK[1], 0, 0, 0);
        accV[0] = __builtin_amdgcn_mfma_f32_16x16x32_f16(ah0, bv, accV[0], 0, 0, 0);
        accV[1] = __builtin_amdgcn_mfma_f32_16x16x32_f16(ah1, bv, accV[1], 0, 0, 0);

        if (ks < 31) write_stage(cur ^ 1);
        __syncthreads();
    }

    // epilogue: D layout col = lane&15, row = (lane>>4)*4 + r
    #pragma unroll
    for (int rb = 0; rb < 2; ++rb)
        #pragma unroll
        for (int r = 0; r < 4; ++r) {
            const int m = m0 + rb * 16 + hi * 4 + r;
            const int n = w * 16 + lo;
            const size_t idx = (size_t)m * DHEAD + n;
            float vq = accQ[rb][r];
            f16 hq = (f16)vq;
            Qh[idx] = hq; Ql[idx] = (f16)(vq - (float)hq);
            float vk = accK[rb][r];
            f16 hk = (f16)vk;
            Kh[idx] = hk; Kl[idx] = (f16)(vk - (float)hk);
            const int bb = m >> 11, l = m & 2047;
            Vtb[((size_t)bb * DHEAD + n) * SEQ + l] = f2bf(accV[rb][r]);
        }
}

// ---------------------------------------------------------------------------
// Kernel 2: causal tanh-capped attention (r8 structure, measured ~38us).
// P = exp(30*tanh(s)-30) = exp2(-86.5617/(exp2(0.2551*s_raw)+1)) in [8.8e-27,1]
// 8 waves = (wq 0..3) x (wk 0..1): 64 q-rows/block, 64-key super-tile/iter.
// K hi/lo + V + mask double-buffered LDS, one barrier/iter, reg-staged.
// 2-way wk merge at end via LDS. Heavy-first qs.
// ---------------------------------------------------------------------------
__global__ __launch_bounds__(512) void attn_kernel(
    const f16* __restrict__ Qh, const f16* __restrict__ Ql,
    const f16* __restrict__ Kh, const f16* __restrict__ Kl,
    const unsigned short* __restrict__ Vtb, const int* __restrict__ mask,
    float* __restrict__ out)
{
    __shared__ f16 Khs[2][64][136];
    __shared__ f16 Kls[2][64][136];
    __shared__ unsigned short Vs[2][128][72];
    __shared__ int Ms[2][64];
    __shared__ unsigned short Plds[8][16][40];

    const int tid  = threadIdx.x;
    const int lane = tid & 63;
    const int w    = tid >> 6;                  // 0..7
    const int lo   = lane & 15;
    const int hi   = lane >> 4;
    const int wq   = w & 3;
    const int wk   = w >> 2;
    const int b    = blockIdx.x;
    const int qs   = 31 - (int)blockIdx.y;      // heavy blocks first
    const int qrow = qs * 64 + wq * 16;
    const int niter = qs + 1;

    const float c2p = 0.25506061907448296f;     // (2*log2e)/sqrt(128)
    const float c1  = -86.561702453337804f;     // -60*log2e

    f16x8 qh[4], ql[4];
    {
        const size_t off = ((size_t)(b * SEQ + qrow + lo)) * DHEAD + hi * 8;
        #pragma unroll
        for (int c = 0; c < 4; ++c) {
            qh[c] = *reinterpret_cast<const f16x8*>(Qh + off + c * 32);
            ql[c] = *reinterpret_cast<const f16x8*>(Ql + off + c * 32);
        }
    }

    const int krow = tid >> 3;                  // 0..63
    const int kcol = (tid & 7) * 16;            // 0..112
    const int vrow = tid >> 2;                  // 0..127
    const int vcol = (tid & 3) * 16;            // 0,16,32,48

    f16x8  rKh0, rKh1, rKl0, rKl1;
    u16x16 rV;
    int    rM = 0;

    auto load_tile = [&](int kb) {
        const size_t koff = ((size_t)(b * SEQ + kb + krow)) * DHEAD + kcol;
        rKh0 = *reinterpret_cast<const f16x8*>(Kh + koff);
        rKh1 = *reinterpret_cast<const f16x8*>(Kh + koff + 8);
        rKl0 = *reinterpret_cast<const f16x8*>(Kl + koff);
        rKl1 = *reinterpret_cast<const f16x8*>(Kl + koff + 8);
        rV   = *reinterpret_cast<const u16x16*>(Vtb + ((size_t)b * DHEAD + vrow) * SEQ + kb + vcol);
        if (tid < 64) rM = mask[b * SEQ + kb + tid];
    };
    auto write_tile = [&](int buf) {
        *reinterpret_cast<f16x8*>(&Khs[buf][krow][kcol])     = rKh0;
        *reinterpret_cast<f16x8*>(&Khs[buf][krow][kcol + 8]) = rKh1;
        *reinterpret_cast<f16x8*>(&Kls[buf][krow][kcol])     = rKl0;
        *reinterpret_cast<f16x8*>(&Kls[buf][krow][kcol + 8]) = rKl1;
        *reinterpret_cast<u16x16*>(&Vs[buf][vrow][vcol]) = rV;
        if (tid < 64) Ms[buf][tid] = rM;
    };

    load_tile(0);
    write_tile(0);
    __syncthreads();

    f32x4 acc[8] = {};
    float rs[4] = {0.f, 0.f, 0.f, 0.f};

    for (int it = 0; it < niter; ++it) {
        const int cur = it & 1;
        if (it + 1 < niter) load_tile((it + 1) * 64);

        const int kb = it * 64 + wk * 32;
        if (kb <= qrow + 15) {
            #pragma unroll
            for (int h = 0; h < 2; ++h) {
                f32x4 s = {};
                #pragma unroll
                for (int c = 0; c < 4; ++c) {
                    f16x8 fkh = *reinterpret_cast<const f16x8*>(&Khs[cur][wk * 32 + h * 16 + lo][c * 32 + hi * 8]);
                    f16x8 fkl = *reinterpret_cast<const f16x8*>(&Kls[cur][wk * 32 + h * 16 + lo][c * 32 + hi * 8]);
                    s = __builtin_amdgcn_mfma_f32_16x16x32_f16(qh[c], fkh, s, 0, 0, 0);
                    s = __builtin_amdgcn_mfma_f32_16x16x32_f16(qh[c], fkl, s, 0, 0, 0);
                    s = __builtin_amdgcn_mfma_f32_16x16x32_f16(ql[c], fkh, s, 0, 0, 0);
                }
                const int key = kb + h * 16 + lo;
                const int mk  = Ms[cur][wk * 32 + h * 16 + lo];
                #pragma unroll
                for (int r = 0; r < 4; ++r) {
                    const int q = qrow + hi * 4 + r;
                    float t = EXP2(s[r] * c2p);               // e^{2s} (inf ok)
                    float p = EXP2(c1 * fast_rcp(t + 1.0f));
                    p = (key <= q && mk != 0) ? p : 0.0f;     // causal + padding
                    rs[r] += p;
                    Plds[w][hi * 4 + r][h * 16 + lo] = f2bf(p);
                }
            }
            bf16x8 pa = *reinterpret_cast<const bf16x8*>(&Plds[w][lo][hi * 8]);
            #pragma unroll
            for (int dt = 0; dt < 8; ++dt) {
                bf16x8 vf = *reinterpret_cast<const bf16x8*>(&Vs[cur][dt * 16 + lo][wk * 32 + hi * 8]);
                acc[dt] = __builtin_amdgcn_mfma_f32_16x16x32_bf16(pa, vf, acc[dt], 0, 0, 0);
            }
        }

        if (it + 1 < niter) write_tile(cur ^ 1);
        __syncthreads();
    }

    float* red = (float*)&Khs[0][0][0];
    if (wk == 1) {
        float* dst = red + ((size_t)wq * 64 + lane) * 36;
        #pragma unroll
        for (int dt = 0; dt < 8; ++dt)
            #pragma unroll
            for (int r = 0; r < 4; ++r) dst[dt * 4 + r] = acc[dt][r];
        #pragma unroll
        for (int r = 0; r < 4; ++r) dst[32 + r] = rs[r];
    }
    __syncthreads();
    if (wk == 0) {
        const float* src = red + ((size_t)wq * 64 + lane) * 36;
        #pragma unroll
        for (int dt = 0; dt < 8; ++dt)
            #pragma unroll
            for (int r = 0; r < 4; ++r) acc[dt][r] += src[dt * 4 + r];
        float inv[4];
        #pragma unroll
        for (int r = 0; r < 4; ++r) {
            float v = rs[r] + src[32 + r];
            v += __shfl_xor(v, 1);
            v += __shfl_xor(v, 2);
            v += __shfl_xor(v, 4);
            v += __shfl_xor(v, 8);
            inv[r] = fast_rcp(v);
        }
        #pragma unroll
        for (int dt = 0; dt < 8; ++dt)
            #pragma unroll
            for (int r = 0; r < 4; ++r) {
                const size_t q = (size_t)qrow + hi * 4 + r;
                out[((size_t)b * SEQ + q) * DHEAD + dt * 16 + lo] = acc[dt][r] * inv[r];
            }
    }
}

extern "C" void kernel_launch(void* const* d_in, const int* in_sizes, int n_in,
                              void* d_out, int out_size, void* d_ws, size_t ws_size,
                              hipStream_t stream) {
    const float* x   = (const float*)d_in[0];
    const int*   msk = (const int*)d_in[1];
    const float* WQ  = (const float*)d_in[2];
    const float* WK  = (const float*)d_in[3];
    const float* WV  = (const float*)d_in[4];
    float* out = (float*)d_out;

    // ws: Qh|Ql|Kh|Kl (f16) | Vt (bf16) 20MB | Wsp 1.31MB
    const size_t NE = (size_t)BATCH * SEQ * DHEAD;
    f16* Qh = (f16*)d_ws;
    f16* Ql = Qh + NE;
    f16* Kh = Ql + NE;
    f16* Kl = Kh + NE;
    unsigned short* Vtb = (unsigned short*)(Kl + NE);
    f16* Wsp = (f16*)(Vtb + NE);

    wsplit_kernel<<<320, 256, 0, stream>>>(WQ, WK, WV, Wsp);
    proj_kernel<<<dim3(BATCH * SEQ / 32), 512, 0, stream>>>(x, Wsp, Qh, Ql, Kh, Kl, Vtb);
    attn_kernel<<<dim3(BATCH, 32), 512, 0, stream>>>(Qh, Ql, Kh, Kl, Vtb, msk, out);
}